// Round 3
// baseline (522.654 us; speedup 1.0000x reference)
//
#include <hip/hip_runtime.h>
#include <hip/hip_bf16.h>
#include <stdint.h>

#define ALPHA 0.01f

typedef __attribute__((ext_vector_type(8))) short short8;
typedef __attribute__((ext_vector_type(4))) float f32x4;
typedef __attribute__((ext_vector_type(4))) float float4_;
typedef __attribute__((ext_vector_type(4))) unsigned short ushort4_;
typedef unsigned int u32;

// round-to-nearest-even f32 -> bf16 bit pattern
static __device__ __forceinline__ unsigned short f2bf(float f) {
    union { float f; u32 u; } v; v.f = f;
    u32 r = v.u + 0x7FFF + ((v.u >> 16) & 1);
    return (unsigned short)(r >> 16);
}

// async global->LDS, 16B per lane. LDS dest must be wave-uniform base + lane*16.
static __device__ __forceinline__ void lds_load16(const void* g, void* l) {
    __builtin_amdgcn_global_load_lds((const __attribute__((address_space(1))) u32*)g,
                                     (__attribute__((address_space(3))) u32*)l, 16, 0, 0);
}

// ---------------------------------------------------------------------------
// Kernel 1: cast W1,W2 to bf16 transposed (WT[n][k] = W[k][n])
__global__ __launch_bounds__(256) void k_prep_w(const float* __restrict__ W1, const float* __restrict__ W2,
                                                unsigned short* __restrict__ W1T, unsigned short* __restrict__ W2T) {
    int bb = blockIdx.x;
    const float* W = (bb & 256) ? W2 : W1;
    unsigned short* WT = (bb & 256) ? W2T : W1T;
    int n = bb & 255, k = threadIdx.x;
    WT[n * 256 + k] = f2bf(W[k * 256 + n]);
}

// Kernel 2: u[v][d] = sum_n W[d][n]*a_half[n]   (v: 0=W1,a1_top 1=W1,a1_bot 2=W2,a2_top 3=W2,a2_bot)
__global__ __launch_bounds__(256) void k_prep_u(const float* __restrict__ W1, const float* __restrict__ a1,
                                                const float* __restrict__ W2, const float* __restrict__ a2,
                                                float* __restrict__ u) {
    int v = blockIdx.x;
    const float* W = (v < 2) ? W1 : W2;
    const float* a = ((v < 2) ? a1 : a2) + (v & 1) * 256;
    int d = threadIdx.x;
    float acc = 0.f;
    for (int n = 0; n < 256; n++) acc += W[d * 256 + n] * a[n];
    u[v * 256 + d] = acc;
}

// Kernel 3: cast inputs to bf16 + compute the 4 score GEMVs in fp32.
// s layout: s[0]=s_q1 (in1·u0), s[1]=s_k1 (in2·u1), s[2]=s_q2 (in2·u2), s[3]=s_k2 (in1·u3); each [16384]
__global__ __launch_bounds__(256) void k_cast_s(const float* __restrict__ in1, const float* __restrict__ in2,
                                                const float* __restrict__ u,
                                                unsigned short* __restrict__ in1b, unsigned short* __restrict__ in2b,
                                                float* __restrict__ s) {
    int gid = blockIdx.x * 4 + (threadIdx.x >> 6);   // one wave per row
    int tensor = gid >> 14;
    int row = gid & 16383;
    int lane = threadIdx.x & 63;
    const float* in = tensor ? in2 : in1;
    unsigned short* outb = tensor ? in2b : in1b;
    const float* uA = u + (tensor ? 256 : 0);
    const float* uB = u + (tensor ? 512 : 768);
    float* sA = s + (tensor ? 1 : 0) * 16384;
    float* sB = s + (tensor ? 2 : 3) * 16384;

    float4_ v = *(const float4_*)(in + row * 256 + lane * 4);
    float4_ ua = *(const float4_*)(uA + lane * 4);
    float4_ ub = *(const float4_*)(uB + lane * 4);
    ushort4_ ob;
    ob.x = f2bf(v.x); ob.y = f2bf(v.y); ob.z = f2bf(v.z); ob.w = f2bf(v.w);
    *(ushort4_*)(outb + row * 256 + lane * 4) = ob;
    float accA = v.x * ua.x + v.y * ua.y + v.z * ua.z + v.w * ua.w;
    float accB = v.x * ub.x + v.y * ub.y + v.z * ub.z + v.w * ub.w;
    for (int off = 32; off; off >>= 1) {
        accA += __shfl_xor(accA, off, 64);
        accB += __shfl_xor(accB, off, 64);
    }
    if (lane == 0) { sA[row] = accA; sB[row] = accB; }
}

// ---------------------------------------------------------------------------
// Kernel 4: WhT = (W^T) @ (in^T) as bf16 MFMA GEMM.
//   c=0: A=W1T, B=in2b -> whT1[b][d][j] (V^T for attention 1)
//   c=1: A=W2T, B=in1b -> whT2
// M'=256 (d), N'=16384 (i), K=256, 128x128 tiles, BK=32.
__global__ __launch_bounds__(256) void k_gemm_whT(const unsigned short* __restrict__ W1T,
                                                  const unsigned short* __restrict__ W2T,
                                                  const unsigned short* __restrict__ in1b,
                                                  const unsigned short* __restrict__ in2b,
                                                  unsigned short* __restrict__ whT1,
                                                  unsigned short* __restrict__ whT2) {
    __shared__ unsigned short sA[128 * 32];
    __shared__ unsigned short sB[128 * 32];
    int c = blockIdx.x >> 8;
    int bid = blockIdx.x & 255;
    int mt = bid & 1, ntile = bid >> 1;
    const unsigned short* A = c ? W2T : W1T;
    const unsigned short* Bm = c ? in1b : in2b;
    unsigned short* outp = c ? whT2 : whT1;
    int t = threadIdx.x;
    int w = t >> 6, lane = t & 63, l15 = lane & 15, lq = lane >> 4;
    int wm = (w & 1) * 64, wn = (w >> 1) * 64;
    f32x4 acc[4][4] = {};
    // each thread stages 16B for row (t>>2) and row (t>>2)+64 of each 128x32 tile
    const unsigned short* gA = A + (mt * 128 + (t >> 2)) * 256 + (t & 3) * 8;
    const unsigned short* gB = Bm + (ntile * 128 + (t >> 2)) * 256 + (t & 3) * 8;

    for (int kk = 0; kk < 256; kk += 32) {
        lds_load16(gA + kk, &sA[t * 8]);
        lds_load16(gA + kk + 64 * 256, &sA[t * 8 + 2048]);
        lds_load16(gB + kk, &sB[t * 8]);
        lds_load16(gB + kk + 64 * 256, &sB[t * 8 + 2048]);
        __syncthreads();
        short8 af[4], bfr[4];
#pragma unroll
        for (int m2 = 0; m2 < 4; m2++) af[m2] = *(const short8*)&sA[(wm + m2 * 16 + l15) * 32 + lq * 8];
#pragma unroll
        for (int n2 = 0; n2 < 4; n2++) bfr[n2] = *(const short8*)&sB[(wn + n2 * 16 + l15) * 32 + lq * 8];
#pragma unroll
        for (int m2 = 0; m2 < 4; m2++)
#pragma unroll
            for (int n2 = 0; n2 < 4; n2++)
                acc[m2][n2] = __builtin_amdgcn_mfma_f32_16x16x32_bf16(af[m2], bfr[n2], acc[m2][n2], 0, 0, 0);
        __syncthreads();
    }
    // D[m=d][n=i] -> whT[b][d][i]  (row = lq*4+r, col = l15)
#pragma unroll
    for (int m2 = 0; m2 < 4; m2++) {
#pragma unroll
        for (int n2 = 0; n2 < 4; n2++) {
            int i_glob = ntile * 128 + wn + n2 * 16 + l15;
            int bb = i_glob >> 11, ii = i_glob & 2047;
#pragma unroll
            for (int r = 0; r < 4; r++) {
                int d = mt * 128 + wm + m2 * 16 + lq * 4 + r;
                outp[bb * (256 * 2048) + d * 2048 + ii] = f2bf(acc[m2][n2][r]);
            }
        }
    }
}

// ---------------------------------------------------------------------------
// Kernel 5: per-row softmax stats (max, 1/sum). grid: a(2) x b(8) x rowgroup(128 of 16 rows)
__global__ __launch_bounds__(256) void k_stats(const float* __restrict__ s,
                                               const float* __restrict__ mask1, const float* __restrict__ mask2,
                                               float* __restrict__ mst, float* __restrict__ ilst) {
    __shared__ float sk[2048];
    __shared__ float mk[2048];
    int a = blockIdx.x >> 10, b = (blockIdx.x >> 7) & 7, rg = blockIdx.x & 127;
    const float* skp = s + (a ? 3 : 1) * 16384 + b * 2048;
    const float* sqp = s + (a ? 2 : 0) * 16384 + b * 2048;
    const float* mp = (a ? mask1 : mask2) + b * 2048;
    for (int j = threadIdx.x; j < 2048; j += 256) { sk[j] = skp[j]; mk[j] = mp[j]; }
    __syncthreads();
    int w = threadIdx.x >> 6, lane = threadIdx.x & 63;
    for (int rr = 0; rr < 4; rr++) {
        int row = rg * 16 + w * 4 + rr;
        float sq = sqp[row];
        float mx = -3.4e38f;
        for (int j = lane; j < 2048; j += 64) {
            float x = sq + sk[j];
            x = fmaxf(x, x * ALPHA) + mk[j];
            mx = fmaxf(mx, x);
        }
        for (int off = 32; off; off >>= 1) mx = fmaxf(mx, __shfl_xor(mx, off, 64));
        float sum = 0.f;
        for (int j = lane; j < 2048; j += 64) {
            float x = sq + sk[j];
            x = fmaxf(x, x * ALPHA) + mk[j];
            sum += __expf(x - mx);
        }
        for (int off = 32; off; off >>= 1) sum += __shfl_xor(sum, off, 64);
        if (lane == 0) {
            int idx = a * 16384 + b * 2048 + row;
            mst[idx] = mx;
            ilst[idx] = 1.0f / sum;
        }
    }
}

// ---------------------------------------------------------------------------
// Kernel 6: fused probs + ctx = P @ V.  grid: a(2) x b(8) x mt(16) x ntile(2) = 512 blocks.
// Each block: 128 query rows x full 2048 keys, 128 of 256 ctx columns.
__global__ __launch_bounds__(256) void k_attn(const float* __restrict__ s,
                                              const float* __restrict__ mst, const float* __restrict__ ilst,
                                              const unsigned short* __restrict__ whT1,
                                              const unsigned short* __restrict__ whT2,
                                              const float* __restrict__ mask1, const float* __restrict__ mask2,
                                              float* __restrict__ out) {
    __shared__ unsigned short sP[128 * 40];  // stride 40 (80B, 16B-aligned) kills write bank conflicts
    __shared__ unsigned short sV[128 * 32];
    __shared__ float lsk[2048];
    __shared__ float lmk[2048];
    __shared__ float lsq[128], lm[128], lil[128];

    int a = blockIdx.x >> 8;
    int bid = blockIdx.x & 255;
    int b = bid >> 5, mt = (bid >> 1) & 15, ntile = bid & 1;
    int t = threadIdx.x;
    const float* skp = s + (a ? 3 : 1) * 16384 + b * 2048;
    const float* sqp = s + (a ? 2 : 0) * 16384 + b * 2048 + mt * 128;
    const float* mp = (a ? mask1 : mask2) + b * 2048;
    const float* mrow = mst + a * 16384 + b * 2048 + mt * 128;
    const float* irow = ilst + a * 16384 + b * 2048 + mt * 128;
    const unsigned short* V = (a ? whT2 : whT1) + b * (256 * 2048) + ntile * 128 * 2048;
    float* pout = out + 8388608 + a * 33554432 + (b * 2048 + mt * 128) * 2048;
    float* cout = out + a * 4194304 + (b * 2048 + mt * 128) * 256 + ntile * 128;

    for (int j = t; j < 2048; j += 256) { lsk[j] = skp[j]; lmk[j] = mp[j]; }
    if (t < 128) { lsq[t] = sqp[t]; lm[t] = mrow[t]; lil[t] = irow[t]; }
    __syncthreads();

    int w = t >> 6, lane = t & 63, l15 = lane & 15, lq = lane >> 4;
    int wm = (w & 1) * 64, wn = (w >> 1) * 64;
    f32x4 acc[4][4] = {};
    int pi = t >> 1;          // P row this thread computes
    int pj = (t & 1) * 16;    // P col base (16 cols)
    const unsigned short* gV = V + (t >> 2) * 2048 + (t & 3) * 8;

    for (int j0 = 0; j0 < 2048; j0 += 32) {
        // async V tile [128 d][32 j]: two 16B issues per thread (rows t>>2 and t>>2+64)
        lds_load16(gV + j0, &sV[t * 8]);
        lds_load16(gV + j0 + 64 * 2048, &sV[t * 8 + 2048]);

        float sqv = lsq[pi], mv = lm[pi], ilv = lil[pi];
        float pv[16];
#pragma unroll
        for (int q = 0; q < 16; q++) {
            float x = sqv + lsk[j0 + pj + q];
            x = fmaxf(x, x * ALPHA) + lmk[j0 + pj + q];
            pv[q] = __expf(x - mv) * ilv;
        }
        if (ntile == 0) {  // wave-uniform branch; write normalized probs fp32
            float4_* gp = (float4_*)(pout + pi * 2048 + j0 + pj);
#pragma unroll
            for (int q4 = 0; q4 < 4; q4++) {
                float4_ vv; vv.x = pv[q4 * 4]; vv.y = pv[q4 * 4 + 1]; vv.z = pv[q4 * 4 + 2]; vv.w = pv[q4 * 4 + 3];
                gp[q4] = vv;
            }
        }
        union { short8 v2[2]; unsigned short u[16]; } pk;
#pragma unroll
        for (int q = 0; q < 16; q++) pk.u[q] = f2bf(pv[q]);
        *(short8*)&sP[pi * 40 + pj] = pk.v2[0];
        *(short8*)&sP[pi * 40 + pj + 8] = pk.v2[1];
        __syncthreads();

        short8 af[4], bfr[4];
#pragma unroll
        for (int m2 = 0; m2 < 4; m2++) af[m2] = *(const short8*)&sP[(wm + m2 * 16 + l15) * 40 + lq * 8];
#pragma unroll
        for (int n2 = 0; n2 < 4; n2++) bfr[n2] = *(const short8*)&sV[(wn + n2 * 16 + l15) * 32 + lq * 8];
#pragma unroll
        for (int m2 = 0; m2 < 4; m2++)
#pragma unroll
            for (int n2 = 0; n2 < 4; n2++)
                acc[m2][n2] = __builtin_amdgcn_mfma_f32_16x16x32_bf16(af[m2], bfr[n2], acc[m2][n2], 0, 0, 0);
        __syncthreads();
    }
    // ctx epilogue: D[m=i][n=d]
#pragma unroll
    for (int m2 = 0; m2 < 4; m2++) {
#pragma unroll
        for (int n2 = 0; n2 < 4; n2++) {
#pragma unroll
            for (int r = 0; r < 4; r++) {
                int i_loc = wm + m2 * 16 + lq * 4 + r;
                int d_loc = wn + n2 * 16 + l15;
                cout[i_loc * 256 + d_loc] = acc[m2][n2][r];
            }
        }
    }
}

// ---------------------------------------------------------------------------
extern "C" void kernel_launch(void* const* d_in, const int* in_sizes, int n_in,
                              void* d_out, int out_size, void* d_ws, size_t ws_size,
                              hipStream_t stream) {
    const float* in1   = (const float*)d_in[0];
    const float* mask1 = (const float*)d_in[1];
    const float* in2   = (const float*)d_in[2];
    const float* mask2 = (const float*)d_in[3];
    const float* W1    = (const float*)d_in[4];
    const float* a1    = (const float*)d_in[5];
    const float* W2    = (const float*)d_in[6];
    const float* a2    = (const float*)d_in[7];
    float* out = (float*)d_out;
    char* ws = (char*)d_ws;

    unsigned short* in1b = (unsigned short*)(ws);
    unsigned short* in2b = (unsigned short*)(ws + 8388608);
    unsigned short* whT1 = (unsigned short*)(ws + 16777216);
    unsigned short* whT2 = (unsigned short*)(ws + 25165824);
    unsigned short* W1T  = (unsigned short*)(ws + 33554432);
    unsigned short* W2T  = (unsigned short*)(ws + 33685504);
    float* u    = (float*)(ws + 33816576);
    float* s    = (float*)(ws + 33820672);
    float* mst  = (float*)(ws + 34082816);
    float* ilst = (float*)(ws + 34213888);

    k_prep_w<<<512, 256, 0, stream>>>(W1, W2, W1T, W2T);
    k_prep_u<<<4, 256, 0, stream>>>(W1, a1, W2, a2, u);
    k_cast_s<<<8192, 256, 0, stream>>>(in1, in2, u, in1b, in2b, s);
    k_gemm_whT<<<512, 256, 0, stream>>>(W1T, W2T, in1b, in2b, whT1, whT2);
    k_stats<<<2048, 256, 0, stream>>>(s, mask1, mask2, mst, ilst);
    k_attn<<<512, 256, 0, stream>>>(s, mst, ilst, whT1, whT2, mask1, mask2, out);
}